// Round 3
// baseline (244.689 us; speedup 1.0000x reference)
//
#include <hip/hip_runtime.h>

#define B_N 256
#define C_N 50000
#define D_N 512
#define ALPHA 0.5f

// Kernel 1: newc = centers. Pure streaming float4 copy, the 6.3 TB/s m13
// pattern: one-shot (no loop), 4 independent 16B loads then 4 stores per
// thread, coalesced stride-256 within block. 50000*512/4 = 6.4M float4
// = 6250 blocks x 256 threads x 4. No branches, no scalar loads.
__global__ __launch_bounds__(256) void copy_centers(
        const float4* __restrict__ src, float4* __restrict__ dst) {
    int base = blockIdx.x * 1024 + threadIdx.x;
    float4 v0 = src[base];
    float4 v1 = src[base + 256];
    float4 v2 = src[base + 512];
    float4 v3 = src[base + 768];
    dst[base]       = v0;
    dst[base + 256] = v1;
    dst[base + 512] = v2;
    dst[base + 768] = v3;
}

// Kernel 2: recover labels from one-hot rows. No atomics, no counts.
__global__ __launch_bounds__(256) void find_labels(
        const float* __restrict__ onehot,
        int* __restrict__ labels) {
    int t = threadIdx.x;
    int base = blockIdx.x * 1024 + t;                   // float4 index
    const float4* p = (const float4*)onehot;
    float4 v[4];
#pragma unroll
    for (int k = 0; k < 4; ++k) v[k] = p[base + k * 256];
#pragma unroll
    for (int k = 0; k < 4; ++k) {
        float4 q = v[k];
        if (q.x != 0.f || q.y != 0.f || q.z != 0.f || q.w != 0.f) {
            int g = (base + k * 256) * 4;
            float f[4] = {q.x, q.y, q.z, q.w};
#pragma unroll
            for (int j = 0; j < 4; ++j) {
                if (f[j] != 0.f) {
                    int gg = g + j;
                    int b = gg / C_N;
                    int c = gg - b * C_N;
                    labels[b] = c;                      // exactly one writer per b
                }
            }
        }
    }
}

// Kernel 3: result[b] = sum_d (x[b][d] - centers[label_b][d])^2
__global__ __launch_bounds__(128) void sq_dist(
        const float* __restrict__ x,
        const float* __restrict__ centers,
        const int* __restrict__ labels,
        float* __restrict__ result) {
    int b = blockIdx.x;
    int t = threadIdx.x;                                // 0..127
    int lab = labels[b];
    float4 xv = ((const float4*)(x + (size_t)b * D_N))[t];
    float4 cv = ((const float4*)(centers + (size_t)lab * D_N))[t];
    float dx = xv.x - cv.x, dy = xv.y - cv.y, dz = xv.z - cv.z, dw = xv.w - cv.w;
    float s = dx * dx + dy * dy + dz * dz + dw * dw;
#pragma unroll
    for (int off = 32; off > 0; off >>= 1) s += __shfl_down(s, off, 64);
    __shared__ float ws[2];
    if ((t & 63) == 0) ws[t >> 6] = s;
    __syncthreads();
    if (t == 0) result[b] = ws[0] + ws[1];
}

// Kernel 4: rewrite the <=256 touched rows AFTER the copy (stream-ordered).
// One block per sample; block b is canonical iff b is the first sample with
// its class. n derived by counting label matches (no atomics anywhere).
//   new[c] = centers[c]*(1 - a*n/(n+1)) + (a/(n+1)) * sum_{label_b'=c} x[b']
__global__ __launch_bounds__(128) void fixup_touched(
        const float* __restrict__ x,
        const float* __restrict__ centers,
        const int* __restrict__ labels,
        float* __restrict__ newc) {
    __shared__ int sl[B_N];
    int t = threadIdx.x;
    int b = blockIdx.x;
    sl[t] = labels[t];
    sl[t + 128] = labels[t + 128];
    __syncthreads();
    int c = sl[b];
    // canonical check + count (uniform across the block; cheap L1/LDS scan)
    int n = 0;
    bool canonical = true;
    for (int i = 0; i < B_N; ++i) {
        if (sl[i] == c) {
            n++;
            if (i < b) canonical = false;
        }
    }
    if (!canonical) return;
    float4 cv = ((const float4*)(centers + (size_t)c * D_N))[t];
    float4 sx = make_float4(0.f, 0.f, 0.f, 0.f);
    for (int i = 0; i < B_N; ++i) {
        if (sl[i] == c) {
            float4 xv = ((const float4*)(x + (size_t)i * D_N))[t];
            sx.x += xv.x; sx.y += xv.y; sx.z += xv.z; sx.w += xv.w;
        }
    }
    float inv = 1.0f / (float)(n + 1);
    float ac = 1.0f - ALPHA * (float)n * inv;
    float bc = ALPHA * inv;
    float4 res;
    res.x = cv.x * ac + sx.x * bc;
    res.y = cv.y * ac + sx.y * bc;
    res.z = cv.z * ac + sx.z * bc;
    res.w = cv.w * ac + sx.w * bc;
    ((float4*)(newc + (size_t)c * D_N))[t] = res;
}

extern "C" void kernel_launch(void* const* d_in, const int* in_sizes, int n_in,
                              void* d_out, int out_size, void* d_ws, size_t ws_size,
                              hipStream_t stream) {
    const float* x       = (const float*)d_in[0];   // [B, D]
    const float* onehot  = (const float*)d_in[1];   // [B, C]
    const float* centers = (const float*)d_in[2];   // [C, D]
    float* out    = (float*)d_out;
    float* result = out;                            // [B, 1] -> 256 floats
    float* newc   = out + B_N;                      // [C, D]

    int* labels = (int*)d_ws;                       // B ints (fully overwritten)

    copy_centers<<<C_N * D_N / 4 / 1024, 256, 0, stream>>>(
        (const float4*)centers, (float4*)newc);
    find_labels<<<B_N * C_N / 4 / 1024, 256, 0, stream>>>(onehot, labels);
    sq_dist<<<B_N, 128, 0, stream>>>(x, centers, labels, result);
    fixup_touched<<<B_N, 128, 0, stream>>>(x, centers, labels, newc);
}